// Round 1
// baseline (728.326 us; speedup 1.0000x reference)
//
#include <hip/hip_runtime.h>

#define DEV __device__ __forceinline__

typedef unsigned short u16;
typedef float  floatx4 __attribute__((ext_vector_type(4)));
typedef unsigned int uintx4 __attribute__((ext_vector_type(4)));
typedef __bf16 bf16x8 __attribute__((ext_vector_type(8)));

constexpr int cB = 4, cLQ = 1024, cLKV = 2048, cD = 1024, cH = 16, cHD = 64;

DEV u16 f2bf(float f) {
  unsigned u = __builtin_bit_cast(unsigned, f);
  u += 0x7fffu + ((u >> 16) & 1u);       // round-to-nearest-even
  return (u16)(u >> 16);
}

DEV bf16x8 ld_frag(const u16* p) {
  uintx4 u = *(const uintx4*)p;
  return __builtin_bit_cast(bf16x8, u);
}

DEV floatx4 mfma16(bf16x8 a, bf16x8 b, floatx4 c) {
  return __builtin_amdgcn_mfma_f32_16x16x32_bf16(a, b, c, 0, 0, 0);
}

// ---------------------------------------------------------------------------
// lengths[b] = number of unmasked keys (mask is a monotone suffix of True).
// Handles mask arriving as int32 (0/1) OR raw uint8 bools via in-kernel
// detection: in a packed-bool buffer, any aligned run of four 1-bytes reads
// as 0x01010101 (>1) when viewed as int32.
// ---------------------------------------------------------------------------
__global__ void lens_kernel(const void* __restrict__ mask, int* __restrict__ lens) {
  __shared__ int smode;
  __shared__ int cnt[cB];
  int tid = threadIdx.x;                  // 256 threads, 1 block
  if (tid == 0) smode = 0;
  if (tid < cB) cnt[tid] = 0;
  __syncthreads();
  const unsigned* mi = (const unsigned*)mask;
  int bad = 0;
  for (int i = tid; i < cB * cLKV / 4; i += 256) {  // safe under both layouts
    if (mi[i] > 1u) bad = 1;
  }
  if (bad) smode = 1;
  __syncthreads();
  if (smode == 0) {                       // int32 mask
    for (int b = 0; b < cB; b++) {
      int c = 0;
      for (int i = tid; i < cLKV; i += 256) c += (mi[(size_t)b * cLKV + i] == 0u);
      atomicAdd(&cnt[b], c);
    }
  } else {                                // uint8 mask
    const unsigned char* m8 = (const unsigned char*)mask;
    for (int b = 0; b < cB; b++) {
      int c = 0;
      for (int i = tid; i < cLKV; i += 256) c += (m8[(size_t)b * cLKV + i] == 0);
      atomicAdd(&cnt[b], c);
    }
  }
  __syncthreads();
  if (tid < cB) lens[tid] = cnt[tid];
}

// ---------------------------------------------------------------------------
// LayerNorm over D=1024, one block (256 thr) per row, bf16 output.
// ---------------------------------------------------------------------------
__global__ __launch_bounds__(256) void ln_kernel(
    const float* __restrict__ x, const float* __restrict__ w,
    const float* __restrict__ b, u16* __restrict__ out) {
  int row = blockIdx.x, tid = threadIdx.x;
  const float4* xr = (const float4*)(x + (size_t)row * cD);
  float4 v = xr[tid];
  __shared__ float sbuf[8];
  float s = v.x + v.y + v.z + v.w;
  #pragma unroll
  for (int m = 1; m < 64; m <<= 1) s += __shfl_xor(s, m, 64);
  if ((tid & 63) == 0) sbuf[tid >> 6] = s;
  __syncthreads();
  float mean = (sbuf[0] + sbuf[1] + sbuf[2] + sbuf[3]) * (1.f / cD);
  float dx = v.x - mean, dy = v.y - mean, dz = v.z - mean, dw = v.w - mean;
  float ss = dx * dx + dy * dy + dz * dz + dw * dw;
  #pragma unroll
  for (int m = 1; m < 64; m <<= 1) ss += __shfl_xor(ss, m, 64);
  if ((tid & 63) == 0) sbuf[4 + (tid >> 6)] = ss;
  __syncthreads();
  float var = (sbuf[4] + sbuf[5] + sbuf[6] + sbuf[7]) * (1.f / cD);
  float rs = rsqrtf(var + 1e-5f);
  float4 wv = ((const float4*)w)[tid];
  float4 bv = ((const float4*)b)[tid];
  ushort4 o;
  o.x = f2bf(dx * rs * wv.x + bv.x);
  o.y = f2bf(dy * rs * wv.y + bv.y);
  o.z = f2bf(dz * rs * wv.z + bv.z);
  o.w = f2bf(dw * rs * wv.w + bv.w);
  ((ushort4*)(out + (size_t)row * cD))[tid] = o;
}

// fp32 -> bf16 cast, vectorized x4
__global__ __launch_bounds__(256) void cast_kernel(
    const float* __restrict__ in, u16* __restrict__ out, int n4) {
  int i = blockIdx.x * 256 + threadIdx.x;
  if (i < n4) {
    float4 v = ((const float4*)in)[i];
    ushort4 o;
    o.x = f2bf(v.x); o.y = f2bf(v.y); o.z = f2bf(v.z); o.w = f2bf(v.w);
    ((ushort4*)out)[i] = o;
  }
}

// ---------------------------------------------------------------------------
// C[M,N] = A[M,K] @ B[N,K]^T + bias[N] (+ res[M,N]); A,B bf16 row-major.
// Block = 4 waves; wave w -> 16 rows; 64x64 C tile per block.
// MFMA 16x16x32 bf16: A-frag lane: m=lane&15, k=(lane>>4)*8+j (16B load).
// C/D layout: col=lane&15, row=(lane>>4)*4+reg.
// ---------------------------------------------------------------------------
template<bool OUT_BF16, bool RES>
__global__ __launch_bounds__(256) void gemm_bt(
    const u16* __restrict__ A, const u16* __restrict__ Bm,
    const float* __restrict__ bias, const float* __restrict__ res,
    void* __restrict__ Cout, int M, int N, int K) {
  int wave = threadIdx.x >> 6, lane = threadIdx.x & 63;
  int m16 = lane & 15, quad = lane >> 4;
  int rowA = blockIdx.y * 64 + wave * 16 + m16;
  int n0 = blockIdx.x * 64;
  const u16* pa = A + (size_t)rowA * K + quad * 8;
  const u16* pb = Bm + (size_t)(n0 + m16) * K + quad * 8;
  floatx4 z = {0.f, 0.f, 0.f, 0.f};
  floatx4 acc[4] = {z, z, z, z};
  for (int k0 = 0; k0 < K; k0 += 32) {
    bf16x8 a = ld_frag(pa + k0);
    #pragma unroll
    for (int nb = 0; nb < 4; nb++) {
      bf16x8 b = ld_frag(pb + (size_t)nb * 16 * K + k0);
      acc[nb] = mfma16(a, b, acc[nb]);
    }
  }
  int crow = blockIdx.y * 64 + wave * 16 + quad * 4;
  #pragma unroll
  for (int nb = 0; nb < 4; nb++) {
    int col = n0 + nb * 16 + m16;
    float bs = bias[col];
    #pragma unroll
    for (int r = 0; r < 4; r++) {
      float v = acc[nb][r] + bs;
      size_t idx = (size_t)(crow + r) * N + col;
      if (RES) v += res[idx];
      if (OUT_BF16) ((u16*)Cout)[idx] = f2bf(v);
      else          ((float*)Cout)[idx] = v;
    }
  }
}

// ---------------------------------------------------------------------------
// Flash cross-attention. qh: [B,LQ,H,64] bf16; kvh: [B,LKV,2,H,64] bf16.
// Block = (qt, h, b), 4 waves, 64 q-rows/block (16/wave). K-chunks of 32.
// Masked keys handled by loop bound (exact: exp(-1e9 - m) == 0 in fp32).
// ---------------------------------------------------------------------------
__global__ __launch_bounds__(256) void attn_kernel(
    const u16* __restrict__ qh, const u16* __restrict__ kvh,
    const int* __restrict__ lens, u16* __restrict__ out) {
  int qt = blockIdx.x, h = blockIdx.y, b = blockIdx.z;
  int len = lens[b];
  int wave = threadIdx.x >> 6, lane = threadIdx.x & 63;
  int m16 = lane & 15, quad = lane >> 4;

  __shared__ __align__(16) u16 Kt[32][72];     // keys x d, padded (bank spread)
  __shared__ __align__(16) u16 VtT[64][40];    // d x keys (transposed), padded
  __shared__ __align__(16) u16 Ps[4][16][40];  // per-wave P round-trip

  int qrow = qt * 64 + wave * 16 + m16;
  const u16* qp = qh + ((size_t)(b * cLQ + qrow) * cH + h) * cHD;
  bf16x8 aq0 = ld_frag(qp + quad * 8);         // d in [0,32)
  bf16x8 aq1 = ld_frag(qp + 32 + quad * 8);    // d in [32,64)

  float mi[4] = {-1e30f, -1e30f, -1e30f, -1e30f};
  float li[4] = {0.f, 0.f, 0.f, 0.f};
  floatx4 z = {0.f, 0.f, 0.f, 0.f};
  floatx4 accO[4] = {z, z, z, z};

  int st_row = threadIdx.x >> 3;   // 0..31 key row
  int st_seg = threadIdx.x & 7;    // 0..7  d segment of 8
  const u16* kvb = kvh + (size_t)b * cLKV * (2 * cD) + h * cHD;
  uintx4 zv = {0, 0, 0, 0};

  for (int k0 = 0; k0 < len; k0 += 32) {
    __syncthreads();   // protect K/V tiles from previous iteration readers
    int kk = k0 + st_row;
    uintx4 kd = zv, vd = zv;
    if (kk < len) {
      const u16* rowp = kvb + (size_t)kk * (2 * cD);
      kd = *(const uintx4*)(rowp + st_seg * 8);
      vd = *(const uintx4*)(rowp + cD + st_seg * 8);
    }
    *(uintx4*)&Kt[st_row][st_seg * 8] = kd;
    u16 vv[8];
    *(uintx4*)vv = vd;
    #pragma unroll
    for (int j = 0; j < 8; j++) VtT[st_seg * 8 + j][st_row] = vv[j];
    __syncthreads();

    // S = Q K^T * scale, two 16-key blocks
    floatx4 s0, s1;
    {
      bf16x8 bk0 = ld_frag(&Kt[m16][quad * 8]);
      bf16x8 bk1 = ld_frag(&Kt[m16][32 + quad * 8]);
      floatx4 t = z;
      t = mfma16(aq0, bk0, t);
      t = mfma16(aq1, bk1, t);
      int key = k0 + m16;
      #pragma unroll
      for (int r = 0; r < 4; r++) t[r] = (key < len) ? t[r] * 0.125f : -1e9f;
      s0 = t;
    }
    {
      bf16x8 bk0 = ld_frag(&Kt[16 + m16][quad * 8]);
      bf16x8 bk1 = ld_frag(&Kt[16 + m16][32 + quad * 8]);
      floatx4 t = z;
      t = mfma16(aq0, bk0, t);
      t = mfma16(aq1, bk1, t);
      int key = k0 + 16 + m16;
      #pragma unroll
      for (int r = 0; r < 4; r++) t[r] = (key < len) ? t[r] * 0.125f : -1e9f;
      s1 = t;
    }

    // online softmax (row = quad*4+r, cols spread over the quad's 16 lanes)
    float alpha[4], p0[4], p1[4];
    #pragma unroll
    for (int r = 0; r < 4; r++) {
      float mx = fmaxf(s0[r], s1[r]);
      #pragma unroll
      for (int m = 1; m < 16; m <<= 1) mx = fmaxf(mx, __shfl_xor(mx, m, 64));
      float nm = fmaxf(mi[r], mx);
      float al = __expf(mi[r] - nm);
      float e0 = __expf(s0[r] - nm);
      float e1 = __expf(s1[r] - nm);
      float rs = e0 + e1;
      #pragma unroll
      for (int m = 1; m < 16; m <<= 1) rs += __shfl_xor(rs, m, 64);
      li[r] = li[r] * al + rs;
      mi[r] = nm;
      alpha[r] = al;
      p0[r] = e0;
      p1[r] = e1;
    }
    #pragma unroll
    for (int db = 0; db < 4; db++) {
      floatx4 t = accO[db];
      #pragma unroll
      for (int r = 0; r < 4; r++) t[r] *= alpha[r];
      accO[db] = t;
    }

    // P: C-layout -> LDS -> A-layout (wave-private slice, no barrier needed)
    #pragma unroll
    for (int r = 0; r < 4; r++) {
      Ps[wave][quad * 4 + r][m16] = f2bf(p0[r]);
      Ps[wave][quad * 4 + r][16 + m16] = f2bf(p1[r]);
    }
    bf16x8 ap = ld_frag(&Ps[wave][m16][quad * 8]);
    #pragma unroll
    for (int db = 0; db < 4; db++) {
      bf16x8 bv = ld_frag(&VtT[db * 16 + m16][quad * 8]);
      accO[db] = mfma16(ap, bv, accO[db]);
    }
  }

  // epilogue: O / l, write bf16 [B,LQ,H,64]
  #pragma unroll
  for (int r = 0; r < 4; r++) {
    float inv = 1.0f / li[r];
    int qg = qt * 64 + wave * 16 + quad * 4 + r;
    size_t base = ((size_t)(b * cLQ + qg) * cH + h) * cHD;
    #pragma unroll
    for (int db = 0; db < 4; db++)
      out[base + db * 16 + m16] = f2bf(accO[db][r] * inv);
  }
}

// ---------------------------------------------------------------------------
extern "C" void kernel_launch(void* const* d_in, const int* in_sizes, int n_in,
                              void* d_out, int out_size, void* d_ws, size_t ws_size,
                              hipStream_t stream) {
  const float* q    = (const float*)d_in[0];
  const float* kv   = (const float*)d_in[1];
  const void*  mask = d_in[2];
  const float* nqw  = (const float*)d_in[3];
  const float* nqb  = (const float*)d_in[4];
  const float* nkw  = (const float*)d_in[5];
  const float* nkb  = (const float*)d_in[6];
  const float* Wq   = (const float*)d_in[7];
  const float* bq   = (const float*)d_in[8];
  const float* Wkv  = (const float*)d_in[9];
  const float* bkv  = (const float*)d_in[10];
  const float* Wo   = (const float*)d_in[11];
  const float* bo   = (const float*)d_in[12];
  float* out = (float*)d_out;

  char* w = (char*)d_ws;
  int* lens = (int*)w;       w += 256;
  u16* qn   = (u16*)w;       w += (size_t)cB * cLQ * cD * 2;        // 8 MB
  u16* kvn  = (u16*)w;       w += (size_t)cB * cLKV * cD * 2;       // 16 MB
  u16* wqb  = (u16*)w;       w += (size_t)cD * cD * 2;              // 2 MB
  u16* wkvb = (u16*)w;       w += (size_t)2 * cD * cD * 2;          // 4 MB
  u16* wob  = (u16*)w;       w += (size_t)cD * cD * 2;              // 2 MB
  u16* qhb  = (u16*)w;       w += (size_t)cB * cLQ * cD * 2;        // 8 MB
  u16* kvhb = (u16*)w;       w += (size_t)cB * cLKV * 2 * cD * 2;   // 32 MB
  u16* aob  = (u16*)w;                                              // 8 MB

  lens_kernel<<<1, 256, 0, stream>>>(mask, lens);
  ln_kernel<<<cB * cLQ, 256, 0, stream>>>(q, nqw, nqb, qn);
  ln_kernel<<<cB * cLKV, 256, 0, stream>>>(kv, nkw, nkb, kvn);
  cast_kernel<<<(cD * cD / 4) / 256, 256, 0, stream>>>(Wq, wqb, cD * cD / 4);
  cast_kernel<<<(2 * cD * cD / 4) / 256, 256, 0, stream>>>(Wkv, wkvb, 2 * cD * cD / 4);
  cast_kernel<<<(cD * cD / 4) / 256, 256, 0, stream>>>(Wo, wob, cD * cD / 4);
  gemm_bt<true, false><<<dim3(cD / 64, cB * cLQ / 64), 256, 0, stream>>>(
      qn, wqb, bq, nullptr, qhb, cB * cLQ, cD, cD);
  gemm_bt<true, false><<<dim3(2 * cD / 64, cB * cLKV / 64), 256, 0, stream>>>(
      kvn, wkvb, bkv, nullptr, kvhb, cB * cLKV, 2 * cD, cD);
  attn_kernel<<<dim3(cLQ / 64, cH, cB), 256, 0, stream>>>(qhb, kvhb, lens, aob);
  gemm_bt<false, true><<<dim3(cD / 64, cB * cLQ / 64), 256, 0, stream>>>(
      aob, wob, bo, q, out, cB * cLQ, cD, cD);
}

// Round 2
// 404.680 us; speedup vs baseline: 1.7998x; 1.7998x over previous
//
#include <hip/hip_runtime.h>

#define DEV __device__ __forceinline__

typedef unsigned short u16;
typedef float  floatx4 __attribute__((ext_vector_type(4)));
typedef unsigned int uintx4 __attribute__((ext_vector_type(4)));
typedef __bf16 bf16x8 __attribute__((ext_vector_type(8)));

constexpr int cB = 4, cLQ = 1024, cLKV = 2048, cD = 1024, cH = 16, cHD = 64;

DEV u16 f2bf(float f) {
  unsigned u = __builtin_bit_cast(unsigned, f);
  u += 0x7fffu + ((u >> 16) & 1u);       // round-to-nearest-even
  return (u16)(u >> 16);
}

DEV bf16x8 ld_frag(const u16* p) {
  uintx4 u = *(const uintx4*)p;
  return __builtin_bit_cast(bf16x8, u);
}

DEV floatx4 mfma16(bf16x8 a, bf16x8 b, floatx4 c) {
  return __builtin_amdgcn_mfma_f32_16x16x32_bf16(a, b, c, 0, 0, 0);
}

// async global->LDS, 16 B per lane. LDS dest = wave-uniform base + lane*16.
DEV void g2lds(const u16* g, u16* l) {
  __builtin_amdgcn_global_load_lds(
      (const __attribute__((address_space(1))) void*)g,
      (__attribute__((address_space(3))) void*)l, 16, 0, 0);
}

// ---------------------------------------------------------------------------
// lengths[b] = number of unmasked keys (mask is a monotone suffix of True).
// Handles mask as int32 (0/1) or uint8 bools via in-kernel detection.
// ---------------------------------------------------------------------------
__global__ void lens_kernel(const void* __restrict__ mask, int* __restrict__ lens) {
  __shared__ int smode;
  __shared__ int cnt[cB];
  int tid = threadIdx.x;                  // 256 threads, 1 block
  if (tid == 0) smode = 0;
  if (tid < cB) cnt[tid] = 0;
  __syncthreads();
  const unsigned* mi = (const unsigned*)mask;
  int bad = 0;
  for (int i = tid; i < cB * cLKV / 4; i += 256) {
    if (mi[i] > 1u) bad = 1;
  }
  if (bad) smode = 1;
  __syncthreads();
  if (smode == 0) {                       // int32 mask
    for (int b = 0; b < cB; b++) {
      int c = 0;
      for (int i = tid; i < cLKV; i += 256) c += (mi[(size_t)b * cLKV + i] == 0u);
      atomicAdd(&cnt[b], c);
    }
  } else {                                // uint8 mask
    const unsigned char* m8 = (const unsigned char*)mask;
    for (int b = 0; b < cB; b++) {
      int c = 0;
      for (int i = tid; i < cLKV; i += 256) c += (m8[(size_t)b * cLKV + i] == 0);
      atomicAdd(&cnt[b], c);
    }
  }
  __syncthreads();
  if (tid < cB) lens[tid] = cnt[tid];
}

// ---------------------------------------------------------------------------
// LayerNorm over D=1024, one block (256 thr) per row, bf16 output.
// ---------------------------------------------------------------------------
__global__ __launch_bounds__(256) void ln_kernel(
    const float* __restrict__ x, const float* __restrict__ w,
    const float* __restrict__ b, u16* __restrict__ out) {
  int row = blockIdx.x, tid = threadIdx.x;
  const float4* xr = (const float4*)(x + (size_t)row * cD);
  float4 v = xr[tid];
  __shared__ float sbuf[8];
  float s = v.x + v.y + v.z + v.w;
  #pragma unroll
  for (int m = 1; m < 64; m <<= 1) s += __shfl_xor(s, m, 64);
  if ((tid & 63) == 0) sbuf[tid >> 6] = s;
  __syncthreads();
  float mean = (sbuf[0] + sbuf[1] + sbuf[2] + sbuf[3]) * (1.f / cD);
  float dx = v.x - mean, dy = v.y - mean, dz = v.z - mean, dw = v.w - mean;
  float ss = dx * dx + dy * dy + dz * dz + dw * dw;
  #pragma unroll
  for (int m = 1; m < 64; m <<= 1) ss += __shfl_xor(ss, m, 64);
  if ((tid & 63) == 0) sbuf[4 + (tid >> 6)] = ss;
  __syncthreads();
  float var = (sbuf[4] + sbuf[5] + sbuf[6] + sbuf[7]) * (1.f / cD);
  float rs = rsqrtf(var + 1e-5f);
  float4 wv = ((const float4*)w)[tid];
  float4 bv = ((const float4*)b)[tid];
  ushort4 o;
  o.x = f2bf(dx * rs * wv.x + bv.x);
  o.y = f2bf(dy * rs * wv.y + bv.y);
  o.z = f2bf(dz * rs * wv.z + bv.z);
  o.w = f2bf(dw * rs * wv.w + bv.w);
  ((ushort4*)(out + (size_t)row * cD))[tid] = o;
}

// fp32 -> bf16 cast, vectorized x4
__global__ __launch_bounds__(256) void cast_kernel(
    const float* __restrict__ in, u16* __restrict__ out, int n4) {
  int i = blockIdx.x * 256 + threadIdx.x;
  if (i < n4) {
    float4 v = ((const float4*)in)[i];
    ushort4 o;
    o.x = f2bf(v.x); o.y = f2bf(v.y); o.z = f2bf(v.z); o.w = f2bf(v.w);
    ((ushort4*)out)[i] = o;
  }
}

// ---------------------------------------------------------------------------
// m97-structure GEMM: C[M,N] = A[M,K] @ B[N,K]^T + bias[N] (+ res[M,N]).
// 128x128 C-tile/block, BK=32, LDS staging via global_load_lds width=16.
// 4 waves in 2x2; each wave computes 64x64 = 4x4 MFMA 16x16x32 tiles.
// Per K-iter: 4 global_load_lds_dwordx4 + 8 ds_read_b128 + 16 MFMA.
// LDS tiles are [128][32] UNPADDED (global_load_lds lane order requires it).
// Requires M%128==0, N%128==0, K%32==0 (true for all three call sites).
// ---------------------------------------------------------------------------
template<bool OUT_BF16, bool RES>
__global__ __launch_bounds__(256) void gemm_bt(
    const u16* __restrict__ A, const u16* __restrict__ Bm,
    const float* __restrict__ bias, const float* __restrict__ res,
    void* __restrict__ Cout, int M, int N, int K) {
  __shared__ __align__(16) u16 As[128 * 32];
  __shared__ __align__(16) u16 Bs[128 * 32];
  int tid = threadIdx.x;
  int wave = tid >> 6, lane = tid & 63;
  int m16 = lane & 15, quad = lane >> 4;
  int wr = wave >> 1, wc = wave & 1;

  int row0 = blockIdx.y * 128;
  int col0 = blockIdx.x * 128;

  // staging: round p (p=0,1): rows p*64 + wave*16 + lane/4, k-seg (lane&3)*8
  int srow = wave * 16 + (lane >> 2);
  int sseg = (lane & 3) * 8;
  const u16* ga = A + (size_t)(row0 + srow) * K + sseg;
  const u16* gb = Bm + (size_t)(col0 + srow) * K + sseg;
  u16* lA = As + wave * 512 + lane * 8;   // == wave-uniform base + lane*16B
  u16* lB = Bs + wave * 512 + lane * 8;

  floatx4 z = {0.f, 0.f, 0.f, 0.f};
  floatx4 acc[4][4];
  #pragma unroll
  for (int i = 0; i < 4; i++)
    #pragma unroll
    for (int j = 0; j < 4; j++) acc[i][j] = z;

  const size_t rstep = (size_t)64 * K;    // second staging round: rows +64
  for (int k0 = 0; k0 < K; k0 += 32) {
    __syncthreads();                      // prior-tile readers done
    g2lds(ga + k0, lA);
    g2lds(ga + rstep + k0, lA + 2048);
    g2lds(gb + k0, lB);
    g2lds(gb + rstep + k0, lB + 2048);
    __syncthreads();                      // drains vmcnt(0), tile visible

    bf16x8 af[4], bfr[4];
    #pragma unroll
    for (int i = 0; i < 4; i++)
      af[i] = ld_frag(&As[(wr * 64 + i * 16 + m16) * 32 + quad * 8]);
    #pragma unroll
    for (int j = 0; j < 4; j++)
      bfr[j] = ld_frag(&Bs[(wc * 64 + j * 16 + m16) * 32 + quad * 8]);
    #pragma unroll
    for (int i = 0; i < 4; i++)
      #pragma unroll
      for (int j = 0; j < 4; j++)
        acc[i][j] = mfma16(af[i], bfr[j], acc[i][j]);
  }

  // epilogue: C/D layout col=lane&15, row=quad*4+reg
  #pragma unroll
  for (int j = 0; j < 4; j++) {
    int col = col0 + wc * 64 + j * 16 + m16;
    float bs = bias[col];
    #pragma unroll
    for (int i = 0; i < 4; i++) {
      int crow = row0 + wr * 64 + i * 16 + quad * 4;
      #pragma unroll
      for (int r = 0; r < 4; r++) {
        float v = acc[i][j][r] + bs;
        size_t idx = (size_t)(crow + r) * N + col;
        if (RES) v += res[idx];
        if (OUT_BF16) ((u16*)Cout)[idx] = f2bf(v);
        else          ((float*)Cout)[idx] = v;
      }
    }
  }
}

// ---------------------------------------------------------------------------
// Flash cross-attention. qh: [B,LQ,H,64] bf16; kvh: [B,LKV,2,H,64] bf16.
// Block = (qt, h, b), 4 waves, 64 q-rows/block (16/wave). K-chunks of 32.
// Masked keys handled by loop bound (exact: exp(-1e9 - m) == 0 in fp32).
// ---------------------------------------------------------------------------
__global__ __launch_bounds__(256) void attn_kernel(
    const u16* __restrict__ qh, const u16* __restrict__ kvh,
    const int* __restrict__ lens, u16* __restrict__ out) {
  int qt = blockIdx.x, h = blockIdx.y, b = blockIdx.z;
  int len = lens[b];
  int wave = threadIdx.x >> 6, lane = threadIdx.x & 63;
  int m16 = lane & 15, quad = lane >> 4;

  __shared__ __align__(16) u16 Kt[32][72];     // keys x d, padded (bank spread)
  __shared__ __align__(16) u16 VtT[64][40];    // d x keys (transposed), padded
  __shared__ __align__(16) u16 Ps[4][16][40];  // per-wave P round-trip

  int qrow = qt * 64 + wave * 16 + m16;
  const u16* qp = qh + ((size_t)(b * cLQ + qrow) * cH + h) * cHD;
  bf16x8 aq0 = ld_frag(qp + quad * 8);         // d in [0,32)
  bf16x8 aq1 = ld_frag(qp + 32 + quad * 8);    // d in [32,64)

  float mi[4] = {-1e30f, -1e30f, -1e30f, -1e30f};
  float li[4] = {0.f, 0.f, 0.f, 0.f};
  floatx4 z = {0.f, 0.f, 0.f, 0.f};
  floatx4 accO[4] = {z, z, z, z};

  int st_row = threadIdx.x >> 3;   // 0..31 key row
  int st_seg = threadIdx.x & 7;    // 0..7  d segment of 8
  const u16* kvb = kvh + (size_t)b * cLKV * (2 * cD) + h * cHD;
  uintx4 zv = {0, 0, 0, 0};

  for (int k0 = 0; k0 < len; k0 += 32) {
    __syncthreads();   // protect K/V tiles from previous iteration readers
    int kk = k0 + st_row;
    uintx4 kd = zv, vd = zv;
    if (kk < len) {
      const u16* rowp = kvb + (size_t)kk * (2 * cD);
      kd = *(const uintx4*)(rowp + st_seg * 8);
      vd = *(const uintx4*)(rowp + cD + st_seg * 8);
    }
    *(uintx4*)&Kt[st_row][st_seg * 8] = kd;
    u16 vv[8];
    *(uintx4*)vv = vd;
    #pragma unroll
    for (int j = 0; j < 8; j++) VtT[st_seg * 8 + j][st_row] = vv[j];
    __syncthreads();

    // S = Q K^T * scale, two 16-key blocks
    floatx4 s0, s1;
    {
      bf16x8 bk0 = ld_frag(&Kt[m16][quad * 8]);
      bf16x8 bk1 = ld_frag(&Kt[m16][32 + quad * 8]);
      floatx4 t = z;
      t = mfma16(aq0, bk0, t);
      t = mfma16(aq1, bk1, t);
      int key = k0 + m16;
      #pragma unroll
      for (int r = 0; r < 4; r++) t[r] = (key < len) ? t[r] * 0.125f : -1e9f;
      s0 = t;
    }
    {
      bf16x8 bk0 = ld_frag(&Kt[16 + m16][quad * 8]);
      bf16x8 bk1 = ld_frag(&Kt[16 + m16][32 + quad * 8]);
      floatx4 t = z;
      t = mfma16(aq0, bk0, t);
      t = mfma16(aq1, bk1, t);
      int key = k0 + 16 + m16;
      #pragma unroll
      for (int r = 0; r < 4; r++) t[r] = (key < len) ? t[r] * 0.125f : -1e9f;
      s1 = t;
    }

    // online softmax (row = quad*4+r, cols spread over the quad's 16 lanes)
    float alpha[4], p0[4], p1[4];
    #pragma unroll
    for (int r = 0; r < 4; r++) {
      float mx = fmaxf(s0[r], s1[r]);
      #pragma unroll
      for (int m = 1; m < 16; m <<= 1) mx = fmaxf(mx, __shfl_xor(mx, m, 64));
      float nm = fmaxf(mi[r], mx);
      float al = __expf(mi[r] - nm);
      float e0 = __expf(s0[r] - nm);
      float e1 = __expf(s1[r] - nm);
      float rs = e0 + e1;
      #pragma unroll
      for (int m = 1; m < 16; m <<= 1) rs += __shfl_xor(rs, m, 64);
      li[r] = li[r] * al + rs;
      mi[r] = nm;
      alpha[r] = al;
      p0[r] = e0;
      p1[r] = e1;
    }
    #pragma unroll
    for (int db = 0; db < 4; db++) {
      floatx4 t = accO[db];
      #pragma unroll
      for (int r = 0; r < 4; r++) t[r] *= alpha[r];
      accO[db] = t;
    }

    // P: C-layout -> LDS -> A-layout (wave-private slice, no barrier needed)
    #pragma unroll
    for (int r = 0; r < 4; r++) {
      Ps[wave][quad * 4 + r][m16] = f2bf(p0[r]);
      Ps[wave][quad * 4 + r][16 + m16] = f2bf(p1[r]);
    }
    bf16x8 ap = ld_frag(&Ps[wave][m16][quad * 8]);
    #pragma unroll
    for (int db = 0; db < 4; db++) {
      bf16x8 bv = ld_frag(&VtT[db * 16 + m16][quad * 8]);
      accO[db] = mfma16(ap, bv, accO[db]);
    }
  }

  // epilogue: O / l, write bf16 [B,LQ,H,64]
  #pragma unroll
  for (int r = 0; r < 4; r++) {
    float inv = 1.0f / li[r];
    int qg = qt * 64 + wave * 16 + quad * 4 + r;
    size_t base = ((size_t)(b * cLQ + qg) * cH + h) * cHD;
    #pragma unroll
    for (int db = 0; db < 4; db++)
      out[base + db * 16 + m16] = f2bf(accO[db][r] * inv);
  }
}

// ---------------------------------------------------------------------------
extern "C" void kernel_launch(void* const* d_in, const int* in_sizes, int n_in,
                              void* d_out, int out_size, void* d_ws, size_t ws_size,
                              hipStream_t stream) {
  const float* q    = (const float*)d_in[0];
  const float* kv   = (const float*)d_in[1];
  const void*  mask = d_in[2];
  const float* nqw  = (const float*)d_in[3];
  const float* nqb  = (const float*)d_in[4];
  const float* nkw  = (const float*)d_in[5];
  const float* nkb  = (const float*)d_in[6];
  const float* Wq   = (const float*)d_in[7];
  const float* bq   = (const float*)d_in[8];
  const float* Wkv  = (const float*)d_in[9];
  const float* bkv  = (const float*)d_in[10];
  const float* Wo   = (const float*)d_in[11];
  const float* bo   = (const float*)d_in[12];
  float* out = (float*)d_out;

  char* w = (char*)d_ws;
  int* lens = (int*)w;       w += 256;
  u16* qn   = (u16*)w;       w += (size_t)cB * cLQ * cD * 2;        // 8 MB
  u16* kvn  = (u16*)w;       w += (size_t)cB * cLKV * cD * 2;       // 16 MB
  u16* wqb  = (u16*)w;       w += (size_t)cD * cD * 2;              // 2 MB
  u16* wkvb = (u16*)w;       w += (size_t)2 * cD * cD * 2;          // 4 MB
  u16* wob  = (u16*)w;       w += (size_t)cD * cD * 2;              // 2 MB
  u16* qhb  = (u16*)w;       w += (size_t)cB * cLQ * cD * 2;        // 8 MB
  u16* kvhb = (u16*)w;       w += (size_t)cB * cLKV * 2 * cD * 2;   // 32 MB
  u16* aob  = (u16*)w;                                              // 8 MB

  lens_kernel<<<1, 256, 0, stream>>>(mask, lens);
  ln_kernel<<<cB * cLQ, 256, 0, stream>>>(q, nqw, nqb, qn);
  ln_kernel<<<cB * cLKV, 256, 0, stream>>>(kv, nkw, nkb, kvn);
  cast_kernel<<<(cD * cD / 4) / 256, 256, 0, stream>>>(Wq, wqb, cD * cD / 4);
  cast_kernel<<<(2 * cD * cD / 4) / 256, 256, 0, stream>>>(Wkv, wkvb, 2 * cD * cD / 4);
  cast_kernel<<<(cD * cD / 4) / 256, 256, 0, stream>>>(Wo, wob, cD * cD / 4);
  gemm_bt<true, false><<<dim3(cD / 128, cB * cLQ / 128), 256, 0, stream>>>(
      qn, wqb, bq, nullptr, qhb, cB * cLQ, cD, cD);
  gemm_bt<true, false><<<dim3(2 * cD / 128, cB * cLKV / 128), 256, 0, stream>>>(
      kvn, wkvb, bkv, nullptr, kvhb, cB * cLKV, 2 * cD, cD);
  attn_kernel<<<dim3(cLQ / 64, cH, cB), 256, 0, stream>>>(qhb, kvhb, lens, aob);
  gemm_bt<false, true><<<dim3(cD / 128, cB * cLQ / 128), 256, 0, stream>>>(
      aob, wob, bo, q, out, cB * cLQ, cD, cD);
}

// Round 3
// 370.342 us; speedup vs baseline: 1.9666x; 1.0927x over previous
//
#include <hip/hip_runtime.h>

#define DEV __device__ __forceinline__

typedef unsigned short u16;
typedef float  floatx4 __attribute__((ext_vector_type(4)));
typedef unsigned int uintx4 __attribute__((ext_vector_type(4)));
typedef __bf16 bf16x8 __attribute__((ext_vector_type(8)));

constexpr int cB = 4, cLQ = 1024, cLKV = 2048, cD = 1024, cH = 16, cHD = 64;

DEV u16 f2bf(float f) {
  unsigned u = __builtin_bit_cast(unsigned, f);
  u += 0x7fffu + ((u >> 16) & 1u);       // round-to-nearest-even
  return (u16)(u >> 16);
}

DEV bf16x8 ld_frag(const u16* p) {
  uintx4 u = *(const uintx4*)p;
  return __builtin_bit_cast(bf16x8, u);
}

DEV floatx4 mfma16(bf16x8 a, bf16x8 b, floatx4 c) {
  return __builtin_amdgcn_mfma_f32_16x16x32_bf16(a, b, c, 0, 0, 0);
}

// async global->LDS, 16 B per lane. LDS dest = wave-uniform base + lane*16.
DEV void g2lds(const u16* g, u16* l) {
  __builtin_amdgcn_global_load_lds(
      (const __attribute__((address_space(1))) void*)g,
      (__attribute__((address_space(3))) void*)l, 16, 0, 0);
}

// ---------------------------------------------------------------------------
// lengths[b] = number of unmasked keys (mask is a monotone suffix of True).
// ---------------------------------------------------------------------------
__global__ void lens_kernel(const void* __restrict__ mask, int* __restrict__ lens) {
  __shared__ int smode;
  __shared__ int cnt[cB];
  int tid = threadIdx.x;                  // 256 threads, 1 block
  if (tid == 0) smode = 0;
  if (tid < cB) cnt[tid] = 0;
  __syncthreads();
  const unsigned* mi = (const unsigned*)mask;
  int bad = 0;
  for (int i = tid; i < cB * cLKV / 4; i += 256) {
    if (mi[i] > 1u) bad = 1;
  }
  if (bad) smode = 1;
  __syncthreads();
  if (smode == 0) {                       // int32 mask
    for (int b = 0; b < cB; b++) {
      int c = 0;
      for (int i = tid; i < cLKV; i += 256) c += (mi[(size_t)b * cLKV + i] == 0u);
      atomicAdd(&cnt[b], c);
    }
  } else {                                // uint8 mask
    const unsigned char* m8 = (const unsigned char*)mask;
    for (int b = 0; b < cB; b++) {
      int c = 0;
      for (int i = tid; i < cLKV; i += 256) c += (m8[(size_t)b * cLKV + i] == 0);
      atomicAdd(&cnt[b], c);
    }
  }
  __syncthreads();
  if (tid < cB) lens[tid] = cnt[tid];
}

// ---------------------------------------------------------------------------
// LayerNorm over D=1024, one block (256 thr) per row, bf16 output.
// ---------------------------------------------------------------------------
__global__ __launch_bounds__(256) void ln_kernel(
    const float* __restrict__ x, const float* __restrict__ w,
    const float* __restrict__ b, u16* __restrict__ out) {
  int row = blockIdx.x, tid = threadIdx.x;
  const float4* xr = (const float4*)(x + (size_t)row * cD);
  float4 v = xr[tid];
  __shared__ float sbuf[8];
  float s = v.x + v.y + v.z + v.w;
  #pragma unroll
  for (int m = 1; m < 64; m <<= 1) s += __shfl_xor(s, m, 64);
  if ((tid & 63) == 0) sbuf[tid >> 6] = s;
  __syncthreads();
  float mean = (sbuf[0] + sbuf[1] + sbuf[2] + sbuf[3]) * (1.f / cD);
  float dx = v.x - mean, dy = v.y - mean, dz = v.z - mean, dw = v.w - mean;
  float ss = dx * dx + dy * dy + dz * dz + dw * dw;
  #pragma unroll
  for (int m = 1; m < 64; m <<= 1) ss += __shfl_xor(ss, m, 64);
  if ((tid & 63) == 0) sbuf[4 + (tid >> 6)] = ss;
  __syncthreads();
  float var = (sbuf[4] + sbuf[5] + sbuf[6] + sbuf[7]) * (1.f / cD);
  float rs = rsqrtf(var + 1e-5f);
  float4 wv = ((const float4*)w)[tid];
  float4 bv = ((const float4*)b)[tid];
  ushort4 o;
  o.x = f2bf(dx * rs * wv.x + bv.x);
  o.y = f2bf(dy * rs * wv.y + bv.y);
  o.z = f2bf(dz * rs * wv.z + bv.z);
  o.w = f2bf(dw * rs * wv.w + bv.w);
  ((ushort4*)(out + (size_t)row * cD))[tid] = o;
}

// fp32 -> bf16 cast, vectorized x4
__global__ __launch_bounds__(256) void cast_kernel(
    const float* __restrict__ in, u16* __restrict__ out, int n4) {
  int i = blockIdx.x * 256 + threadIdx.x;
  if (i < n4) {
    float4 v = ((const float4*)in)[i];
    ushort4 o;
    o.x = f2bf(v.x); o.y = f2bf(v.y); o.z = f2bf(v.z); o.w = f2bf(v.w);
    ((ushort4*)out)[i] = o;
  }
}

// ---------------------------------------------------------------------------
// m97-structure GEMM: C[M,N] = A[M,K] @ B[N,K]^T + bias[N].
// MODE 0: C bf16 row-major (Q proj).
// MODE 1: KV split epilogue: K head-major -> Cout  [b][h][kv][64]
//                            V transposed -> Cout2 [b][h][d][LKV]
//         (C-layout gives 4 consecutive kv rows per lane -> ushort4 store)
// MODE 2: C f32 row-major + residual (O proj).
// ---------------------------------------------------------------------------
template<int MODE>
__global__ __launch_bounds__(256) void gemm_bt(
    const u16* __restrict__ A, const u16* __restrict__ Bm,
    const float* __restrict__ bias, const float* __restrict__ res,
    void* __restrict__ Cout, void* __restrict__ Cout2, int M, int N, int K) {
  __shared__ __align__(16) u16 As[128 * 32];
  __shared__ __align__(16) u16 Bs[128 * 32];
  int tid = threadIdx.x;
  int wave = tid >> 6, lane = tid & 63;
  int m16 = lane & 15, quad = lane >> 4;
  int wr = wave >> 1, wc = wave & 1;

  int row0 = blockIdx.y * 128;
  int col0 = blockIdx.x * 128;

  int srow = wave * 16 + (lane >> 2);
  int sseg = (lane & 3) * 8;
  const u16* ga = A + (size_t)(row0 + srow) * K + sseg;
  const u16* gb = Bm + (size_t)(col0 + srow) * K + sseg;
  u16* lA = As + wave * 512 + lane * 8;
  u16* lB = Bs + wave * 512 + lane * 8;

  floatx4 z = {0.f, 0.f, 0.f, 0.f};
  floatx4 acc[4][4];
  #pragma unroll
  for (int i = 0; i < 4; i++)
    #pragma unroll
    for (int j = 0; j < 4; j++) acc[i][j] = z;

  const size_t rstep = (size_t)64 * K;
  for (int k0 = 0; k0 < K; k0 += 32) {
    __syncthreads();
    g2lds(ga + k0, lA);
    g2lds(ga + rstep + k0, lA + 2048);
    g2lds(gb + k0, lB);
    g2lds(gb + rstep + k0, lB + 2048);
    __syncthreads();

    bf16x8 af[4], bfr[4];
    #pragma unroll
    for (int i = 0; i < 4; i++)
      af[i] = ld_frag(&As[(wr * 64 + i * 16 + m16) * 32 + quad * 8]);
    #pragma unroll
    for (int j = 0; j < 4; j++)
      bfr[j] = ld_frag(&Bs[(wc * 64 + j * 16 + m16) * 32 + quad * 8]);
    #pragma unroll
    for (int i = 0; i < 4; i++)
      #pragma unroll
      for (int j = 0; j < 4; j++)
        acc[i][j] = mfma16(af[i], bfr[j], acc[i][j]);
  }

  // epilogue: C/D layout col=lane&15, row=quad*4+reg
  #pragma unroll
  for (int j = 0; j < 4; j++) {
    int col = col0 + wc * 64 + j * 16 + m16;
    float bs = bias[col];
    if (MODE == 1) {
      bool isK = col < cD;
      int c2 = isK ? col : col - cD;
      int hh = c2 >> 6, dd = c2 & 63;
      #pragma unroll
      for (int i = 0; i < 4; i++) {
        int crow = row0 + wr * 64 + i * 16 + quad * 4;
        int bb = crow >> 11, kvp = crow & (cLKV - 1);
        if (isK) {
          u16* dst = (u16*)Cout + ((size_t)(bb * cH + hh) * cLKV + kvp) * 64 + dd;
          #pragma unroll
          for (int r = 0; r < 4; r++) dst[(size_t)r * 64] = f2bf(acc[i][j][r] + bs);
        } else {
          u16* dst = (u16*)Cout2 + ((size_t)(bb * cH + hh) * 64 + dd) * cLKV + kvp;
          ushort4 o;
          o.x = f2bf(acc[i][j][0] + bs);
          o.y = f2bf(acc[i][j][1] + bs);
          o.z = f2bf(acc[i][j][2] + bs);
          o.w = f2bf(acc[i][j][3] + bs);
          *(ushort4*)dst = o;
        }
      }
    } else {
      #pragma unroll
      for (int i = 0; i < 4; i++) {
        int crow = row0 + wr * 64 + i * 16 + quad * 4;
        #pragma unroll
        for (int r = 0; r < 4; r++) {
          float v = acc[i][j][r] + bs;
          size_t idx = (size_t)(crow + r) * N + col;
          if (MODE == 2) ((float*)Cout)[idx] = v + res[idx];
          else           ((u16*)Cout)[idx] = f2bf(v);
        }
      }
    }
  }
}

// ---------------------------------------------------------------------------
// Flash cross-attention v2.
// qh: [B,LQ,H,64] bf16; kh: [B,H,LKV,64] bf16; vth: [B,H,64,LKV] bf16.
// 1-D grid, b fastest (load balance). 4 waves, 64 q-rows/block, K-chunk 64.
// LDS tiles padded to stride 88 u16 (176 B: 16B-aligned, 2-way conflict=free).
// No in-kernel transpose: V^T precomputed by the KV-proj GEMM epilogue.
// ---------------------------------------------------------------------------
__global__ __launch_bounds__(256) void attn_kernel(
    const u16* __restrict__ qh, const u16* __restrict__ kh,
    const u16* __restrict__ vth, const int* __restrict__ lens,
    u16* __restrict__ out) {
  int gid = blockIdx.x;
  int b = gid & (cB - 1);
  int h = (gid >> 2) & (cH - 1);
  int qt = gid >> 6;
  int len = lens[b];
  int wave = threadIdx.x >> 6, lane = threadIdx.x & 63;
  int m16 = lane & 15, quad = lane >> 4;

  constexpr int KS = 88;                        // padded LDS row stride (u16)
  __shared__ __align__(16) u16 Kt[64 * KS];     // [key][d]
  __shared__ __align__(16) u16 Vt[64 * KS];     // [d][key]
  __shared__ __align__(16) u16 Ps[4][16 * KS];  // per-wave P round-trip

  int qrow = qt * 64 + wave * 16 + m16;
  const u16* qp = qh + ((size_t)(b * cLQ + qrow) * cH + h) * cHD;
  bf16x8 aq0 = ld_frag(qp + quad * 8);          // d in [0,32)
  bf16x8 aq1 = ld_frag(qp + 32 + quad * 8);     // d in [32,64)

  const u16* kbase = kh + (size_t)(b * cH + h) * cLKV * cHD;
  const u16* vbase = vth + (size_t)(b * cH + h) * cHD * cLKV;

  int srow = threadIdx.x >> 3;   // 0..31
  int sseg = threadIdx.x & 7;    // 0..7 (16B segment)

  float mi[4] = {-1e30f, -1e30f, -1e30f, -1e30f};
  float li[4] = {0.f, 0.f, 0.f, 0.f};
  floatx4 z = {0.f, 0.f, 0.f, 0.f};
  floatx4 accO[4] = {z, z, z, z};

  for (int k0 = 0; k0 < len; k0 += 64) {        // k0+64 <= 2048 always
    __syncthreads();                            // prior-tile readers done
    {
      const u16* kg = kbase + (size_t)(k0 + srow) * cHD + sseg * 8;
      const u16* vg = vbase + (size_t)srow * cLKV + k0 + sseg * 8;
      uintx4 ka = *(const uintx4*)kg;
      uintx4 kb2 = *(const uintx4*)(kg + (size_t)32 * cHD);
      uintx4 va = *(const uintx4*)vg;
      uintx4 vb = *(const uintx4*)(vg + (size_t)32 * cLKV);
      *(uintx4*)&Kt[srow * KS + sseg * 8] = ka;
      *(uintx4*)&Kt[(srow + 32) * KS + sseg * 8] = kb2;
      *(uintx4*)&Vt[srow * KS + sseg * 8] = va;
      *(uintx4*)&Vt[(srow + 32) * KS + sseg * 8] = vb;
    }
    __syncthreads();

    // S = Q K^T * scale: 4 col-tiles of 16 keys
    floatx4 s[4];
    #pragma unroll
    for (int t = 0; t < 4; t++) {
      bf16x8 bk0 = ld_frag(&Kt[(t * 16 + m16) * KS + quad * 8]);
      bf16x8 bk1 = ld_frag(&Kt[(t * 16 + m16) * KS + 32 + quad * 8]);
      floatx4 tt = z;
      tt = mfma16(aq0, bk0, tt);
      tt = mfma16(aq1, bk1, tt);
      int key = k0 + t * 16 + m16;
      #pragma unroll
      for (int r = 0; r < 4; r++)
        s[t][r] = (key < len) ? tt[r] * 0.125f : -1e9f;
    }

    // online softmax: one 16-lane reduce per row per 64 keys
    float alpha[4];
    #pragma unroll
    for (int r = 0; r < 4; r++) {
      float mx = fmaxf(fmaxf(s[0][r], s[1][r]), fmaxf(s[2][r], s[3][r]));
      #pragma unroll
      for (int m = 1; m < 16; m <<= 1) mx = fmaxf(mx, __shfl_xor(mx, m, 64));
      float nm = fmaxf(mi[r], mx);
      float al = __expf(mi[r] - nm);
      float e0 = __expf(s[0][r] - nm);
      float e1 = __expf(s[1][r] - nm);
      float e2 = __expf(s[2][r] - nm);
      float e3 = __expf(s[3][r] - nm);
      float rs = (e0 + e1) + (e2 + e3);
      #pragma unroll
      for (int m = 1; m < 16; m <<= 1) rs += __shfl_xor(rs, m, 64);
      li[r] = li[r] * al + rs;
      mi[r] = nm;
      alpha[r] = al;
      int prow = (quad * 4 + r) * KS + m16;
      Ps[wave][prow] = f2bf(e0);
      Ps[wave][prow + 16] = f2bf(e1);
      Ps[wave][prow + 32] = f2bf(e2);
      Ps[wave][prow + 48] = f2bf(e3);
    }
    #pragma unroll
    for (int db = 0; db < 4; db++) {
      floatx4 t = accO[db];
      #pragma unroll
      for (int r = 0; r < 4; r++) t[r] *= alpha[r];
      accO[db] = t;
    }

    // P (A-layout) x V^T tiles
    bf16x8 ap0 = ld_frag(&Ps[wave][m16 * KS + quad * 8]);
    bf16x8 ap1 = ld_frag(&Ps[wave][m16 * KS + 32 + quad * 8]);
    #pragma unroll
    for (int db = 0; db < 4; db++) {
      bf16x8 bv0 = ld_frag(&Vt[(db * 16 + m16) * KS + quad * 8]);
      bf16x8 bv1 = ld_frag(&Vt[(db * 16 + m16) * KS + 32 + quad * 8]);
      accO[db] = mfma16(ap0, bv0, accO[db]);
      accO[db] = mfma16(ap1, bv1, accO[db]);
    }
  }

  // epilogue: O / l, write bf16 [B,LQ,H,64]
  #pragma unroll
  for (int r = 0; r < 4; r++) {
    float inv = 1.0f / li[r];
    int qg = qt * 64 + wave * 16 + quad * 4 + r;
    size_t base = ((size_t)(b * cLQ + qg) * cH + h) * cHD;
    #pragma unroll
    for (int db = 0; db < 4; db++)
      out[base + db * 16 + m16] = f2bf(accO[db][r] * inv);
  }
}

// ---------------------------------------------------------------------------
extern "C" void kernel_launch(void* const* d_in, const int* in_sizes, int n_in,
                              void* d_out, int out_size, void* d_ws, size_t ws_size,
                              hipStream_t stream) {
  const float* q    = (const float*)d_in[0];
  const float* kv   = (const float*)d_in[1];
  const void*  mask = d_in[2];
  const float* nqw  = (const float*)d_in[3];
  const float* nqb  = (const float*)d_in[4];
  const float* nkw  = (const float*)d_in[5];
  const float* nkb  = (const float*)d_in[6];
  const float* Wq   = (const float*)d_in[7];
  const float* bq   = (const float*)d_in[8];
  const float* Wkv  = (const float*)d_in[9];
  const float* bkv  = (const float*)d_in[10];
  const float* Wo   = (const float*)d_in[11];
  const float* bo   = (const float*)d_in[12];
  float* out = (float*)d_out;

  char* w = (char*)d_ws;
  int* lens = (int*)w;       w += 256;
  u16* qn   = (u16*)w;       w += (size_t)cB * cLQ * cD * 2;        // 8 MB
  u16* kvn  = (u16*)w;       w += (size_t)cB * cLKV * cD * 2;       // 16 MB
  u16* wqb  = (u16*)w;       w += (size_t)cD * cD * 2;              // 2 MB
  u16* wkvb = (u16*)w;       w += (size_t)2 * cD * cD * 2;          // 4 MB
  u16* wob  = (u16*)w;       w += (size_t)cD * cD * 2;              // 2 MB
  u16* qhb  = (u16*)w;       w += (size_t)cB * cLQ * cD * 2;        // 8 MB
  u16* khb  = (u16*)w;       w += (size_t)cB * cH * cLKV * cHD * 2; // 16 MB
  u16* vthb = (u16*)w;       w += (size_t)cB * cH * cHD * cLKV * 2; // 16 MB
  u16* aob  = (u16*)w;                                              // 8 MB

  lens_kernel<<<1, 256, 0, stream>>>(mask, lens);
  ln_kernel<<<cB * cLQ, 256, 0, stream>>>(q, nqw, nqb, qn);
  ln_kernel<<<cB * cLKV, 256, 0, stream>>>(kv, nkw, nkb, kvn);
  cast_kernel<<<(cD * cD / 4) / 256, 256, 0, stream>>>(Wq, wqb, cD * cD / 4);
  cast_kernel<<<(2 * cD * cD / 4) / 256, 256, 0, stream>>>(Wkv, wkvb, 2 * cD * cD / 4);
  cast_kernel<<<(cD * cD / 4) / 256, 256, 0, stream>>>(Wo, wob, cD * cD / 4);
  gemm_bt<0><<<dim3(cD / 128, cB * cLQ / 128), 256, 0, stream>>>(
      qn, wqb, bq, nullptr, qhb, nullptr, cB * cLQ, cD, cD);
  gemm_bt<1><<<dim3(2 * cD / 128, cB * cLKV / 128), 256, 0, stream>>>(
      kvn, wkvb, bkv, nullptr, khb, vthb, cB * cLKV, 2 * cD, cD);
  attn_kernel<<<dim3(cB * cH * (cLQ / 64)), 256, 0, stream>>>(
      qhb, khb, vthb, lens, aob);
  gemm_bt<2><<<dim3(cD / 128, cB * cLQ / 128), 256, 0, stream>>>(
      aob, wob, bo, q, out, nullptr, cB * cLQ, cD, cD);
}